// Round 1
// baseline (378.668 us; speedup 1.0000x reference)
//
#include <hip/hip_runtime.h>
#include <stdint.h>
#include <stddef.h>

// MultiHeadAttention: B=2, S=2048, D=1024, H=16, Dh=64
// Round 1: correctness-first bf16-MFMA baseline.
//   proj_gemm_kernel x3 : qp/kp/vp = X @ W^T + b  (fp32 in, bf16 out, head-major layout)
//   attn_kernel         : flash attention, swapped-QK^T softmax, fp32 accum, fp32 out

#define NH  16
#define DH  64
#define SEQ 2048
#define DM  1024
#define NB  2

typedef float  f32x4  __attribute__((ext_vector_type(4)));
typedef __bf16 bf16x8 __attribute__((ext_vector_type(8)));

__device__ __forceinline__ __bf16 f2bf(float f) { return (__bf16)f; }

// ---------------------------------------------------------------------------
// Projection GEMM (NT): D[m][n] = sum_k X[m][k] * W[n][k] + bias[n]
// m = b*SEQ + s (4096), n = h*DH + dh (1024), K = 1024.
// Output written bf16 to head-major dst[((b*NH+h)*SEQ+s)*DH + dh].
// 256 thr = 4 waves, block tile 128x128, wave tile 64x64 (4x4 of 16x16x32 MFMA).
// Fragments loaded direct from global (fp32) with fused cvt — no LDS this round.
// ---------------------------------------------------------------------------
__global__ __launch_bounds__(256) void proj_gemm_kernel(
    const float* __restrict__ X, const float* __restrict__ W,
    const float* __restrict__ bias, __bf16* __restrict__ dst)
{
    const int lane = threadIdx.x & 63;
    const int wv   = threadIdx.x >> 6;
    const int m0 = blockIdx.x * 128 + (wv >> 1) * 64;
    const int n0 = blockIdx.y * 128 + (wv & 1) * 64;
    const int lr = lane & 15;          // A-row / B-row within 16-tile
    const int lk = (lane >> 4) * 8;    // k-offset of this lane's 8 contiguous elems

    f32x4 acc[4][4];
#pragma unroll
    for (int i = 0; i < 4; ++i)
#pragma unroll
        for (int j = 0; j < 4; ++j) acc[i][j] = (f32x4){0.f, 0.f, 0.f, 0.f};

    for (int k = 0; k < DM; k += 32) {
        bf16x8 a[4], b[4];
#pragma unroll
        for (int t = 0; t < 4; ++t) {
            const float* pa = X + (size_t)(m0 + t * 16 + lr) * DM + k + lk;
            float4 f0 = *(const float4*)pa;
            float4 f1 = *(const float4*)(pa + 4);
            bf16x8 va;
            va[0] = f2bf(f0.x); va[1] = f2bf(f0.y); va[2] = f2bf(f0.z); va[3] = f2bf(f0.w);
            va[4] = f2bf(f1.x); va[5] = f2bf(f1.y); va[6] = f2bf(f1.z); va[7] = f2bf(f1.w);
            a[t] = va;
            const float* pw = W + (size_t)(n0 + t * 16 + lr) * DM + k + lk;
            float4 g0 = *(const float4*)pw;
            float4 g1 = *(const float4*)(pw + 4);
            bf16x8 vb;
            vb[0] = f2bf(g0.x); vb[1] = f2bf(g0.y); vb[2] = f2bf(g0.z); vb[3] = f2bf(g0.w);
            vb[4] = f2bf(g1.x); vb[5] = f2bf(g1.y); vb[6] = f2bf(g1.z); vb[7] = f2bf(g1.w);
            b[t] = vb;
        }
#pragma unroll
        for (int mt = 0; mt < 4; ++mt)
#pragma unroll
            for (int nt = 0; nt < 4; ++nt)
                acc[mt][nt] = __builtin_amdgcn_mfma_f32_16x16x32_bf16(
                    a[mt], b[nt], acc[mt][nt], 0, 0, 0);
    }

    // Epilogue: C layout col = lane&15 (n), row = (lane>>4)*4+r (m). Add bias,
    // cast to bf16, scatter into head-major layout.
#pragma unroll
    for (int nt = 0; nt < 4; ++nt) {
        const int n_g = n0 + nt * 16 + lr;
        const float bb = bias[n_g];
        const int h = n_g >> 6, dh = n_g & 63;
#pragma unroll
        for (int mt = 0; mt < 4; ++mt)
#pragma unroll
            for (int r = 0; r < 4; ++r) {
                const int m_g = m0 + mt * 16 + (lane >> 4) * 4 + r;
                const int bi = m_g >> 11;          // batch
                const int s  = m_g & (SEQ - 1);    // seq pos
                dst[((size_t)((bi * NH + h) * SEQ + s)) * DH + dh] =
                    f2bf(acc[mt][nt][r] + bb);
            }
    }
}

// ---------------------------------------------------------------------------
// Flash attention. Block = 256 thr = 4 independent waves, each owns 16 q-rows.
// grid.x = (S/64 qtiles)=32  x  (B*H)=32  -> 1024 blocks.
// Swapped QK^T: S^T[key][q] = mfma(A=K_rows, B=Q_rows) so lane owns ONE q-row
// (col = lane&15) -> softmax = 16 local ops + shfl_xor(16,32) over the 4-lane
// group. P transposed to MFMA-A layout via tiny per-wave LDS buffer; V^T staged
// cooperatively in LDS (write pattern: whole wave writes one row -> conflict-free).
// ---------------------------------------------------------------------------
#define PADK 80   // row stride (bf16 elems): 160B, 16B-aligned for ds_read_b128

__global__ __launch_bounds__(256) void attn_kernel(
    const __bf16* __restrict__ qh, const __bf16* __restrict__ kh,
    const __bf16* __restrict__ vh, float* __restrict__ out)
{
    __shared__ __align__(16) __bf16 v_t[DH][PADK];        // V^T tile [d][key]
    __shared__ __align__(16) __bf16 p_buf[4][16][PADK];   // per-wave P [q][key]

    const int tid  = threadIdx.x;
    const int lane = tid & 63;
    const int wv   = tid >> 6;
    const int qt   = blockIdx.x & 31;
    const int bh   = blockIdx.x >> 5;        // b*NH + h
    const size_t hb = (size_t)bh * SEQ * DH;
    const int q0 = qt * 64 + wv * 16;
    const int lq = lane & 15;
    const int lg = lane >> 4;
    const int lk = lg * 8;

    // Q as MFMA-B operand (fixed for whole kernel): lane holds Q[q0+lq][ks*32+lk..+8]
    bf16x8 bQ[2];
#pragma unroll
    for (int ks = 0; ks < 2; ++ks)
        bQ[ks] = *(const bf16x8*)(qh + hb + (size_t)(q0 + lq) * DH + ks * 32 + lk);

    f32x4 O[4];   // PV accum: dt=0..3 d-tiles; row=(lg*4+r)=q_local, col=lq=d within tile
#pragma unroll
    for (int dt = 0; dt < 4; ++dt) O[dt] = (f32x4){0.f, 0.f, 0.f, 0.f};
    float m2 = -1e30f, l = 0.f;
    const float SC = 0.18033688011116012f;   // log2(e) / sqrt(64)

    for (int t0 = 0; t0 < SEQ; t0 += 64) {
        __syncthreads();   // protect v_t overwrite vs previous tile's PV reads
        // stage V^T: each thread reads 8 bf16 of one key-row, writes them down a column.
        // For fixed j the whole wave writes one LDS row (64 consecutive bf16 = 2-way = free).
#pragma unroll
        for (int it = 0; it < 2; ++it) {
            const int c   = tid + it * 256;
            const int key = c & 63;
            const int dg  = (c >> 6) * 8;
            bf16x8 vr = *(const bf16x8*)(vh + hb + (size_t)(t0 + key) * DH + dg);
#pragma unroll
            for (int j = 0; j < 8; ++j) v_t[dg + j][key] = vr[j];
        }

        // QK^T swapped: sc[kt] holds S^T rows key=t0+kt*16+(lg*4+r), col q=lq
        f32x4 sc[4];
#pragma unroll
        for (int kt = 0; kt < 4; ++kt) {
            f32x4 c = (f32x4){0.f, 0.f, 0.f, 0.f};
#pragma unroll
            for (int ks = 0; ks < 2; ++ks) {
                bf16x8 aK = *(const bf16x8*)(kh + hb +
                    (size_t)(t0 + kt * 16 + lq) * DH + ks * 32 + lk);
                c = __builtin_amdgcn_mfma_f32_16x16x32_bf16(aK, bQ[ks], c, 0, 0, 0);
            }
            sc[kt] = c;
        }

        // online softmax over this tile's 64 keys (distributed: 16 per lane x 4 lanes)
        float tm = -1e30f;
#pragma unroll
        for (int kt = 0; kt < 4; ++kt)
#pragma unroll
            for (int r = 0; r < 4; ++r) {
                sc[kt][r] *= SC;
                tm = fmaxf(tm, sc[kt][r]);
            }
        tm = fmaxf(tm, __shfl_xor(tm, 16));
        tm = fmaxf(tm, __shfl_xor(tm, 32));
        const float mnew = fmaxf(m2, tm);
        const float scl  = exp2f(m2 - mnew);
        m2 = mnew;

        float ls = 0.f;
        __bf16 pb[16];
#pragma unroll
        for (int kt = 0; kt < 4; ++kt)
#pragma unroll
            for (int r = 0; r < 4; ++r) {
                const float p = exp2f(sc[kt][r] - mnew);
                ls += p;
                pb[kt * 4 + r] = f2bf(p);
            }
        ls += __shfl_xor(ls, 16);
        ls += __shfl_xor(ls, 32);
        l = l * scl + ls;

        // rescale O: O-row r corresponds to q_local = lg*4+r; scale lives at lane q_local
#pragma unroll
        for (int r = 0; r < 4; ++r) {
            const float sr = __shfl(scl, lg * 4 + r);
#pragma unroll
            for (int dt = 0; dt < 4; ++dt) O[dt][r] *= sr;
        }

        // write P (bf16) to per-wave LDS in [q][key] layout for MFMA-A reads
#pragma unroll
        for (int kt = 0; kt < 4; ++kt) {
            union { __bf16 h[2]; unsigned int u; } w0, w1;
            w0.h[0] = pb[kt * 4 + 0]; w0.h[1] = pb[kt * 4 + 1];
            w1.h[0] = pb[kt * 4 + 2]; w1.h[1] = pb[kt * 4 + 3];
            const int kb = kt * 16 + lg * 4;
            *(unsigned int*)&p_buf[wv][lq][kb]     = w0.u;
            *(unsigned int*)&p_buf[wv][lq][kb + 2] = w1.u;
        }
        __syncthreads();   // v_t writes visible to all waves (and orders p_buf)

        // PV: O[q][d] += P[q][key] * V[key][d]; A from p_buf rows, B from v_t rows
#pragma unroll
        for (int ks = 0; ks < 2; ++ks) {
            const bf16x8 ap = *(const bf16x8*)&p_buf[wv][lq][ks * 32 + lk];
#pragma unroll
            for (int dt = 0; dt < 4; ++dt) {
                const bf16x8 bv = *(const bf16x8*)&v_t[dt * 16 + lq][ks * 32 + lk];
                O[dt] = __builtin_amdgcn_mfma_f32_16x16x32_bf16(ap, bv, O[dt], 0, 0, 0);
            }
        }
    }

    // epilogue: out[b][s][h*64 + d] = O / l
    const float linv = 1.f / l;
    const int b = bh >> 4, h = bh & 15;
#pragma unroll
    for (int r = 0; r < 4; ++r) {
        const float li = __shfl(linv, lg * 4 + r);
        const int s_g = q0 + lg * 4 + r;
        float* op = out + ((size_t)(b * SEQ + s_g)) * DM + h * DH;
#pragma unroll
        for (int dt = 0; dt < 4; ++dt)
            op[dt * 16 + lq] = O[dt][r] * li;
    }
}

// ---------------------------------------------------------------------------
extern "C" void kernel_launch(void* const* d_in, const int* in_sizes, int n_in,
                              void* d_out, int out_size, void* d_ws, size_t ws_size,
                              hipStream_t stream)
{
    (void)in_sizes; (void)n_in; (void)out_size; (void)ws_size;
    const float* q  = (const float*)d_in[0];
    const float* k  = (const float*)d_in[1];
    const float* v  = (const float*)d_in[2];
    const float* Wq = (const float*)d_in[3];
    const float* bq = (const float*)d_in[4];
    const float* Wk = (const float*)d_in[5];
    const float* bk = (const float*)d_in[6];
    const float* Wv = (const float*)d_in[7];
    const float* bv = (const float*)d_in[8];

    const size_t head_elems = (size_t)NB * NH * SEQ * DH;   // 4.19M
    __bf16* qh = (__bf16*)d_ws;
    __bf16* kh = qh + head_elems;
    __bf16* vh = kh + head_elems;      // total 3 * 8 MB = 25.2 MB of d_ws
    float* out = (float*)d_out;

    dim3 gblk(32, 8), gthr(256);
    proj_gemm_kernel<<<gblk, gthr, 0, stream>>>(q, Wq, bq, qh);
    proj_gemm_kernel<<<gblk, gthr, 0, stream>>>(k, Wk, bk, kh);
    proj_gemm_kernel<<<gblk, gthr, 0, stream>>>(v, Wv, bv, vh);

    attn_kernel<<<dim3(1024), dim3(256), 0, stream>>>(qh, kh, vh, out);
}

// Round 2
// 160.947 us; speedup vs baseline: 2.3528x; 2.3528x over previous
//
#include <hip/hip_runtime.h>
#include <stdint.h>
#include <stddef.h>

// MultiHeadAttention: B=2, S=2048, D=1024, H=16, Dh=64
// Round 2:
//   cvt6       : fp32 -> bf16 pre-convert (q,k,v,Wq,Wk,Wv)
//   proj3      : fused QKV projection GEMMs, m97-style 128^2 tile + global_load_lds
//   attn_kernel: flash attention; K staged in LDS (shared), T14 async-stage split,
//                PADK=72 (conflict-free), XCD-aware head grouping.

#define NH  16
#define DH  64
#define SEQ 2048
#define DM  1024
#define NB  2

typedef float  f32x4  __attribute__((ext_vector_type(4)));
typedef __bf16 bf16x8 __attribute__((ext_vector_type(8)));

__device__ __forceinline__ __bf16 f2bf(float f) { return (__bf16)f; }

__device__ __forceinline__ void gload_lds16(const __bf16* g, __bf16* l) {
    __builtin_amdgcn_global_load_lds(
        (const __attribute__((address_space(1))) void*)g,
        (__attribute__((address_space(3))) void*)l, 16, 0, 0);
}

// ---------------------------------------------------------------------------
// cvt6: fp32 -> bf16, 8 elems/thread. z selects tensor.
// ---------------------------------------------------------------------------
#define ACT_N (NB * SEQ * DM)   // 4194304
#define W_N   (DM * DM)         // 1048576

__global__ __launch_bounds__(256) void cvt6(
    const float* __restrict__ s0, const float* __restrict__ s1,
    const float* __restrict__ s2, const float* __restrict__ s3,
    const float* __restrict__ s4, const float* __restrict__ s5,
    __bf16* __restrict__ d0, __bf16* __restrict__ d1, __bf16* __restrict__ d2,
    __bf16* __restrict__ d3, __bf16* __restrict__ d4, __bf16* __restrict__ d5)
{
    const float* s; __bf16* d; int n;
    switch (blockIdx.z) {
        case 0: s = s0; d = d0; n = ACT_N; break;
        case 1: s = s1; d = d1; n = ACT_N; break;
        case 2: s = s2; d = d2; n = ACT_N; break;
        case 3: s = s3; d = d3; n = W_N;   break;
        case 4: s = s4; d = d4; n = W_N;   break;
        default: s = s5; d = d5; n = W_N;  break;
    }
    const size_t i = ((size_t)blockIdx.x * 256 + threadIdx.x) * 8;
    if (i >= (size_t)n) return;
    float4 f0 = *(const float4*)(s + i);
    float4 f1 = *(const float4*)(s + i + 4);
    bf16x8 o;
    o[0] = f2bf(f0.x); o[1] = f2bf(f0.y); o[2] = f2bf(f0.z); o[3] = f2bf(f0.w);
    o[4] = f2bf(f1.x); o[5] = f2bf(f1.y); o[6] = f2bf(f1.z); o[7] = f2bf(f1.w);
    *(bf16x8*)(d + i) = o;
}

// ---------------------------------------------------------------------------
// proj3: NT GEMM  D[m][n] = sum_k X[m][k]*W[n][k] + bias[n], bf16 in, bf16 out.
// z in {0,1,2} selects (X,W,bias,dst). 128x128 block tile, BK=32, 4 waves,
// global_load_lds staging (m97 structure), head-major scatter epilogue.
// ---------------------------------------------------------------------------
__global__ __launch_bounds__(256) void proj3(
    const __bf16* __restrict__ X0, const __bf16* __restrict__ X1, const __bf16* __restrict__ X2,
    const __bf16* __restrict__ W0, const __bf16* __restrict__ W1, const __bf16* __restrict__ W2,
    const float* __restrict__ b0, const float* __restrict__ b1, const float* __restrict__ b2,
    __bf16* __restrict__ dq, __bf16* __restrict__ dk, __bf16* __restrict__ dv)
{
    __shared__ __align__(16) __bf16 sA[128][32];   // 8 KB, linear for global_load_lds
    __shared__ __align__(16) __bf16 sB[128][32];   // 8 KB

    const __bf16 *X, *W; const float* bias; __bf16* dst;
    if (blockIdx.z == 0)      { X = X0; W = W0; bias = b0; dst = dq; }
    else if (blockIdx.z == 1) { X = X1; W = W1; bias = b1; dst = dk; }
    else                      { X = X2; W = W2; bias = b2; dst = dv; }

    const int lane = threadIdx.x & 63;
    const int wv   = threadIdx.x >> 6;
    const int mb = blockIdx.x * 128;         // block row base
    const int nb = blockIdx.y * 128;         // block col base
    const int lm0 = (wv >> 1) * 64;          // wave tile within block
    const int ln0 = (wv & 1) * 64;
    const int lr = lane & 15;
    const int lk = (lane >> 4) * 8;
    // staging coords: chunk c covers rows 16c..16c+15; lane -> row 16c+(l>>2), col (l&3)*8
    const int srow = lane >> 2;
    const int scol = (lane & 3) * 8;

    f32x4 acc[4][4];
#pragma unroll
    for (int i = 0; i < 4; ++i)
#pragma unroll
        for (int j = 0; j < 4; ++j) acc[i][j] = (f32x4){0.f, 0.f, 0.f, 0.f};

    for (int k0 = 0; k0 < DM; k0 += 32) {
        __syncthreads();   // previous tile's reads done
#pragma unroll
        for (int c = wv * 2; c < wv * 2 + 2; ++c) {
            gload_lds16(X + (size_t)(mb + c * 16 + srow) * DM + k0 + scol, &sA[c * 16][0]);
            gload_lds16(W + (size_t)(nb + c * 16 + srow) * DM + k0 + scol, &sB[c * 16][0]);
        }
        __syncthreads();   // staged (compiler drains vmcnt before barrier)

        bf16x8 a[4], b[4];
#pragma unroll
        for (int t = 0; t < 4; ++t) {
            a[t] = *(const bf16x8*)&sA[lm0 + t * 16 + lr][lk];
            b[t] = *(const bf16x8*)&sB[ln0 + t * 16 + lr][lk];
        }
#pragma unroll
        for (int mt = 0; mt < 4; ++mt)
#pragma unroll
            for (int nt = 0; nt < 4; ++nt)
                acc[mt][nt] = __builtin_amdgcn_mfma_f32_16x16x32_bf16(
                    a[mt], b[nt], acc[mt][nt], 0, 0, 0);
    }

    // epilogue: C col = lane&15 (n), row = (lane>>4)*4+r (m); head-major scatter
#pragma unroll
    for (int nt = 0; nt < 4; ++nt) {
        const int n_g = nb + ln0 + nt * 16 + lr;
        const float bb = bias[n_g];
        const int h = n_g >> 6, dh = n_g & 63;
#pragma unroll
        for (int mt = 0; mt < 4; ++mt)
#pragma unroll
            for (int r = 0; r < 4; ++r) {
                const int m_g = mb + lm0 + mt * 16 + (lane >> 4) * 4 + r;
                const int bi = m_g >> 11;
                const int s  = m_g & (SEQ - 1);
                dst[((size_t)((bi * NH + h) * SEQ + s)) * DH + dh] =
                    f2bf(acc[mt][nt][r] + bb);
            }
    }
}

// ---------------------------------------------------------------------------
// Flash attention. 4 waves x 16 q-rows, KVBLK=64. K and V^T staged in LDS
// (shared across waves); T14 split: next tile's global loads issued before
// current tile's compute. PADK=72 -> 144B stride -> 2-way banks (free).
// XCD-aware remap: each XCD owns 4 complete heads (KV L2-resident).
// ---------------------------------------------------------------------------
#define PADK 72

__global__ __launch_bounds__(256) void attn_kernel(
    const __bf16* __restrict__ qh, const __bf16* __restrict__ kh,
    const __bf16* __restrict__ vh, float* __restrict__ out)
{
    __shared__ __align__(16) __bf16 k_t[64][PADK];        // K tile  [key][d]
    __shared__ __align__(16) __bf16 v_t[DH][PADK];        // V^T tile [d][key]
    __shared__ __align__(16) __bf16 p_buf[4][16][PADK];   // per-wave P [q][key]

    const int tid  = threadIdx.x;
    const int lane = tid & 63;
    const int wv   = tid >> 6;
    // XCD-aware: launch-index i lands on XCD i%8 (round-robin heuristic).
    // Give XCD x heads bh in [4x, 4x+4): KV working set 2 MB, L2-resident.
    const int i    = blockIdx.x;
    const int slot = i >> 3;
    const int bh   = (i & 7) * 4 + (slot >> 5);
    const int qt   = slot & 31;
    const size_t hb = (size_t)bh * SEQ * DH;
    const int q0 = qt * 64 + wv * 16;
    const int lq = lane & 15;
    const int lg = lane >> 4;
    const int lk = lg * 8;
    // staging coords
    const int krow = tid >> 3, kg = (tid & 7) * 8;   // K: rows krow, krow+32
    const int vkey = tid & 63, vdg = (tid >> 6) * 8; // V: d-groups vdg, vdg+32

    bf16x8 bQ[2];
#pragma unroll
    for (int ks = 0; ks < 2; ++ks)
        bQ[ks] = *(const bf16x8*)(qh + hb + (size_t)(q0 + lq) * DH + ks * 32 + lk);

    f32x4 O[4];
#pragma unroll
    for (int dt = 0; dt < 4; ++dt) O[dt] = (f32x4){0.f, 0.f, 0.f, 0.f};
    float m2 = -1e30f, l = 0.f;
    const float SC = 0.18033688011116012f;   // log2(e)/sqrt(64)

    // prologue: loads for tile 0
    bf16x8 rk0 = *(const bf16x8*)(kh + hb + (size_t)krow * DH + kg);
    bf16x8 rk1 = *(const bf16x8*)(kh + hb + (size_t)(krow + 32) * DH + kg);
    bf16x8 rv0 = *(const bf16x8*)(vh + hb + (size_t)vkey * DH + vdg);
    bf16x8 rv1 = *(const bf16x8*)(vh + hb + (size_t)vkey * DH + vdg + 32);

    for (int t0 = 0; t0 < SEQ; t0 += 64) {
        __syncthreads();   // previous compute done; LDS writable
        // stage K (16B writes, bank-balanced)
        *(bf16x8*)&k_t[krow][kg]      = rk0;
        *(bf16x8*)&k_t[krow + 32][kg] = rk1;
        // stage V^T (scalar scatter; per-j a wave writes one contiguous row)
#pragma unroll
        for (int j = 0; j < 8; ++j) v_t[vdg + j][vkey]      = rv0[j];
#pragma unroll
        for (int j = 0; j < 8; ++j) v_t[vdg + 32 + j][vkey] = rv1[j];

        // T14: issue next tile's loads now; they complete under this compute
        const int tn = (t0 + 64) & (SEQ - 1);   // wraps to 0 on last iter (harmless)
        bf16x8 nk0 = *(const bf16x8*)(kh + hb + (size_t)(tn + krow) * DH + kg);
        bf16x8 nk1 = *(const bf16x8*)(kh + hb + (size_t)(tn + krow + 32) * DH + kg);
        bf16x8 nv0 = *(const bf16x8*)(vh + hb + (size_t)(tn + vkey) * DH + vdg);
        bf16x8 nv1 = *(const bf16x8*)(vh + hb + (size_t)(tn + vkey) * DH + vdg + 32);

        __syncthreads();   // k_t/v_t visible

        // QK^T swapped: sc[kt] rows = key (t0+kt*16+lg*4+r), col = q (lq)
        f32x4 sc[4];
#pragma unroll
        for (int kt = 0; kt < 4; ++kt) {
            f32x4 c = (f32x4){0.f, 0.f, 0.f, 0.f};
#pragma unroll
            for (int ks = 0; ks < 2; ++ks) {
                const bf16x8 aK = *(const bf16x8*)&k_t[kt * 16 + lq][ks * 32 + lk];
                c = __builtin_amdgcn_mfma_f32_16x16x32_bf16(aK, bQ[ks], c, 0, 0, 0);
            }
            sc[kt] = c;
        }

        // online softmax (keys distributed 16/lane over 4-lane groups)
        float tm = -1e30f;
#pragma unroll
        for (int kt = 0; kt < 4; ++kt)
#pragma unroll
            for (int r = 0; r < 4; ++r) {
                sc[kt][r] *= SC;
                tm = fmaxf(tm, sc[kt][r]);
            }
        tm = fmaxf(tm, __shfl_xor(tm, 16));
        tm = fmaxf(tm, __shfl_xor(tm, 32));
        const float mnew = fmaxf(m2, tm);
        const float scl  = exp2f(m2 - mnew);
        m2 = mnew;

        float ls = 0.f;
        __bf16 pb[16];
#pragma unroll
        for (int kt = 0; kt < 4; ++kt)
#pragma unroll
            for (int r = 0; r < 4; ++r) {
                const float p = exp2f(sc[kt][r] - mnew);
                ls += p;
                pb[kt * 4 + r] = f2bf(p);
            }
        ls += __shfl_xor(ls, 16);
        ls += __shfl_xor(ls, 32);
        l = l * scl + ls;

#pragma unroll
        for (int r = 0; r < 4; ++r) {
            const float sr = __shfl(scl, lg * 4 + r);
#pragma unroll
            for (int dt = 0; dt < 4; ++dt) O[dt][r] *= sr;
        }

        // P -> per-wave LDS [q][key] (4B writes, <=2-way banks)
#pragma unroll
        for (int kt = 0; kt < 4; ++kt) {
            union { __bf16 h[2]; unsigned int u; } w0, w1;
            w0.h[0] = pb[kt * 4 + 0]; w0.h[1] = pb[kt * 4 + 1];
            w1.h[0] = pb[kt * 4 + 2]; w1.h[1] = pb[kt * 4 + 3];
            const int kb = kt * 16 + lg * 4;
            *(unsigned int*)&p_buf[wv][lq][kb]     = w0.u;
            *(unsigned int*)&p_buf[wv][lq][kb + 2] = w1.u;
        }
        // wave-private: compiler orders p_buf write->read via lgkmcnt; no barrier

        // PV: O[q][d] += P[q][k] * V^T[d][k]
#pragma unroll
        for (int ks = 0; ks < 2; ++ks) {
            const bf16x8 ap = *(const bf16x8*)&p_buf[wv][lq][ks * 32 + lk];
#pragma unroll
            for (int dt = 0; dt < 4; ++dt) {
                const bf16x8 bv = *(const bf16x8*)&v_t[dt * 16 + lq][ks * 32 + lk];
                O[dt] = __builtin_amdgcn_mfma_f32_16x16x32_bf16(ap, bv, O[dt], 0, 0, 0);
            }
        }

        rk0 = nk0; rk1 = nk1; rv0 = nv0; rv1 = nv1;
    }

    const float linv = 1.f / l;
    const int b = bh >> 4, h = bh & 15;
#pragma unroll
    for (int r = 0; r < 4; ++r) {
        const float li = __shfl(linv, lg * 4 + r);
        const int s_g = q0 + lg * 4 + r;
        float* op = out + ((size_t)(b * SEQ + s_g)) * DM + h * DH;
#pragma unroll
        for (int dt = 0; dt < 4; ++dt)
            op[dt * 16 + lq] = O[dt][r] * li;
    }
}

// ---------------------------------------------------------------------------
extern "C" void kernel_launch(void* const* d_in, const int* in_sizes, int n_in,
                              void* d_out, int out_size, void* d_ws, size_t ws_size,
                              hipStream_t stream)
{
    (void)in_sizes; (void)n_in; (void)out_size; (void)ws_size;
    const float* q  = (const float*)d_in[0];
    const float* k  = (const float*)d_in[1];
    const float* v  = (const float*)d_in[2];
    const float* Wq = (const float*)d_in[3];
    const float* bq = (const float*)d_in[4];
    const float* Wk = (const float*)d_in[5];
    const float* bk = (const float*)d_in[6];
    const float* Wv = (const float*)d_in[7];
    const float* bv = (const float*)d_in[8];

    const size_t act = (size_t)ACT_N;       // 4,194,304
    const size_t wn  = (size_t)W_N;         // 1,048,576
    __bf16* qx  = (__bf16*)d_ws;
    __bf16* kx  = qx + act;
    __bf16* vx  = kx + act;
    __bf16* wqb = vx + act;
    __bf16* wkb = wqb + wn;
    __bf16* wvb = wkb + wn;
    __bf16* qhd = wvb + wn;
    __bf16* khd = qhd + act;
    __bf16* vhd = khd + act;                // total 56.6 MB
    float* out = (float*)d_out;

    cvt6<<<dim3(2048, 1, 6), dim3(256), 0, stream>>>(
        q, k, v, Wq, Wk, Wv, qx, kx, vx, wqb, wkb, wvb);
    proj3<<<dim3(32, 8, 3), dim3(256), 0, stream>>>(
        qx, kx, vx, wqb, wkb, wvb, bq, bk, bv, qhd, khd, vhd);
    attn_kernel<<<dim3(1024), dim3(256), 0, stream>>>(qhd, khd, vhd, out);
}